// Round 1
// baseline (81.630 us; speedup 1.0000x reference)
//
#include <hip/hip_runtime.h>

// FastFocalLoss: scalar = -(pos_loss + neg_loss)/num_pos  (or -neg_loss if no pos)
//   neg_loss = sum log(1-o) * o^2 * (1-t)^4     over all elements
//   pos_loss = sum_{t==1} log(o) * (1-o)^2
//   num_pos  = count(t == 1.0)
// Memory-bound streaming reduction: float4 loads, double per-thread accum,
// wave64 shuffle + LDS block reduce, per-block partials in d_ws, tiny final pass.

__device__ __forceinline__ double wave_reduce_add(double v) {
    #pragma unroll
    for (int off = 32; off > 0; off >>= 1) v += __shfl_down(v, off, 64);
    return v;
}

// Block-level reduce of three doubles (256 threads = 4 waves).
__device__ __forceinline__ void block_reduce3(double& neg, double& pos, double& cnt) {
    __shared__ double s_neg[4], s_pos[4], s_cnt[4];
    neg = wave_reduce_add(neg);
    pos = wave_reduce_add(pos);
    cnt = wave_reduce_add(cnt);
    const int lane = threadIdx.x & 63;
    const int wid  = threadIdx.x >> 6;
    if (lane == 0) { s_neg[wid] = neg; s_pos[wid] = pos; s_cnt[wid] = cnt; }
    __syncthreads();
    if (wid == 0) {
        neg = (lane < 4) ? s_neg[lane] : 0.0;
        pos = (lane < 4) ? s_pos[lane] : 0.0;
        cnt = (lane < 4) ? s_cnt[lane] : 0.0;
        #pragma unroll
        for (int off = 2; off > 0; off >>= 1) {
            neg += __shfl_down(neg, off, 64);
            pos += __shfl_down(pos, off, 64);
            cnt += __shfl_down(cnt, off, 64);
        }
    }
}

__device__ __forceinline__ void accum_elem(float o, float t,
                                           double& neg, double& pos, double& cnt) {
    float g  = 1.0f - t;
    float g2 = g * g;
    // neg term: log(1-o) * o^2 * (1-t)^4
    neg += (double)(__logf(1.0f - o) * o * o * (g2 * g2));
    if (t == 1.0f) {
        float io = 1.0f - o;
        pos += (double)(__logf(o) * io * io);
        cnt += 1.0;
    }
}

__global__ __launch_bounds__(256)
void ffl_partial(const float4* __restrict__ out4, const float4* __restrict__ tgt4,
                 long long n4,
                 const float* __restrict__ out_s, const float* __restrict__ tgt_s,
                 long long tail_start, long long n,
                 double* __restrict__ ws) {
    double neg = 0.0, pos = 0.0, cnt = 0.0;
    const long long idx    = (long long)blockIdx.x * blockDim.x + threadIdx.x;
    const long long stride = (long long)gridDim.x * blockDim.x;

    for (long long i = idx; i < n4; i += stride) {
        float4 o = out4[i];
        float4 t = tgt4[i];
        accum_elem(o.x, t.x, neg, pos, cnt);
        accum_elem(o.y, t.y, neg, pos, cnt);
        accum_elem(o.z, t.z, neg, pos, cnt);
        accum_elem(o.w, t.w, neg, pos, cnt);
    }
    // scalar tail (n not divisible by 4)
    for (long long i = tail_start + idx; i < n; i += stride) {
        accum_elem(out_s[i], tgt_s[i], neg, pos, cnt);
    }

    block_reduce3(neg, pos, cnt);
    if (threadIdx.x == 0) {
        ws[3 * (long long)blockIdx.x + 0] = neg;
        ws[3 * (long long)blockIdx.x + 1] = pos;
        ws[3 * (long long)blockIdx.x + 2] = cnt;
    }
}

__global__ __launch_bounds__(256)
void ffl_final(const double* __restrict__ ws, int nparts, float* __restrict__ out) {
    double neg = 0.0, pos = 0.0, cnt = 0.0;
    for (int i = threadIdx.x; i < nparts; i += 256) {
        neg += ws[3 * i + 0];
        pos += ws[3 * i + 1];
        cnt += ws[3 * i + 2];
    }
    block_reduce3(neg, pos, cnt);
    if (threadIdx.x == 0) {
        double r = (cnt == 0.0) ? (-neg) : (-(pos + neg) / cnt);
        out[0] = (float)r;
    }
}

extern "C" void kernel_launch(void* const* d_in, const int* in_sizes, int n_in,
                              void* d_out, int out_size, void* d_ws, size_t ws_size,
                              hipStream_t stream) {
    const float* outp = (const float*)d_in[0];
    const float* tgtp = (const float*)d_in[1];
    const long long n  = (long long)in_sizes[0];
    const long long n4 = n >> 2;            // float4 count
    const long long tail_start = n4 << 2;

    double* ws = (double*)d_ws;
    int blocks = 2048;                       // ~8 blocks/CU worth of waves; grid-stride
    const int max_blocks = (int)(ws_size / (3 * sizeof(double)));
    if (blocks > max_blocks) blocks = max_blocks;
    if (blocks < 1) blocks = 1;

    ffl_partial<<<blocks, 256, 0, stream>>>(
        (const float4*)outp, (const float4*)tgtp, n4,
        outp, tgtp, tail_start, n, ws);
    ffl_final<<<1, 256, 0, stream>>>(ws, blocks, (float*)d_out);
}